// Round 10
// baseline (271.580 us; speedup 1.0000x reference)
//
#include <hip/hip_runtime.h>
#include <hip/hip_bf16.h>
#include <stdint.h>

typedef __attribute__((ext_vector_type(8))) __bf16 bf16x8;
typedef __attribute__((ext_vector_type(4))) float f32x4;
typedef __attribute__((ext_vector_type(4))) int i32x4;
typedef unsigned short u16;

#define N_NODES 51200
#define N_EDGES 819200
#define F_IN 400
#define K1Q 448
#define H_DIM 256
#define C_OUT 2
#define N_GRAPHS 128
#define NODES_PER_GRAPH 400
#define NB_SCAN (N_NODES / 256)   // 200 blocks

__device__ __forceinline__ u16 f2bf(float f) {
  uint32_t u = __builtin_bit_cast(uint32_t, f);
  u = (u + 0x7fffu + ((u >> 16) & 1u)) >> 16;
  return (u16)u;
}
__device__ __forceinline__ float bf2f(u16 s) {
  uint32_t u = ((uint32_t)s) << 16;
  return __builtin_bit_cast(float, u);
}

typedef const __attribute__((address_space(1))) unsigned int* gas_ptr;
typedef __attribute__((address_space(3))) unsigned int* las_ptr;
__device__ __forceinline__ void gl_lds16(const void* g, void* l) {
  __builtin_amdgcn_global_load_lds((gas_ptr)g, (las_ptr)l, 16, 0, 0);
}
__device__ __forceinline__ void wait_vm0()   { asm volatile("s_waitcnt vmcnt(0)" ::: "memory"); }
__device__ __forceinline__ void wait_vm5()   { asm volatile("s_waitcnt vmcnt(5)" ::: "memory"); }
__device__ __forceinline__ void wait_lgkm0() { asm volatile("s_waitcnt lgkmcnt(0)" ::: "memory"); }

// ---------------- degree histogram (counts[d] = in-degree) ----------------
__global__ void k_hist(const int* __restrict__ dst, int* __restrict__ counts, int E) {
  int e = blockIdx.x * 256 + threadIdx.x;
  if (e < E) atomicAdd(&counts[dst[e]], 1);
}

// ---------------- hierarchical scan: phase 1, per-block sums --------------
__global__ __launch_bounds__(256) void k_reduce(const int* __restrict__ counts,
                                                int* __restrict__ bsum) {
  int i = blockIdx.x * 256 + threadIdx.x;
  int v = counts[i];
#pragma unroll
  for (int o = 32; o; o >>= 1) v += __shfl_xor(v, o);
  __shared__ int wsum[4];
  if ((threadIdx.x & 63) == 0) wsum[threadIdx.x >> 6] = v;
  __syncthreads();
  if (threadIdx.x == 0) bsum[blockIdx.x] = wsum[0] + wsum[1] + wsum[2] + wsum[3];
}

// ---------------- phase 2: scan the 200 block sums (one small block) ------
__global__ __launch_bounds__(256) void k_scantop(const int* __restrict__ bsum,
                                                 int* __restrict__ boff,
                                                 int* __restrict__ off_last) {
  __shared__ int s[256];
  int t = threadIdx.x;
  int v = (t < NB_SCAN) ? bsum[t] : 0;
  s[t] = v;
  __syncthreads();
  for (int d = 1; d < 256; d <<= 1) {
    int u = (t >= d) ? s[t - d] : 0;
    __syncthreads();
    s[t] += u;
    __syncthreads();
  }
  if (t < NB_SCAN) boff[t] = s[t] - v;   // exclusive prefix of block sums
  if (t == 0) *off_last = N_EDGES;       // off[N] = total edges
}

// ---------------- phase 3: local scan + block offset; also dis ------------
__global__ __launch_bounds__(256) void k_scanlocal(const int* __restrict__ counts,
                                                   const int* __restrict__ boff,
                                                   int* __restrict__ off,
                                                   int* __restrict__ cursor,
                                                   float* __restrict__ dis) {
  __shared__ int s[256];
  int t = threadIdx.x;
  int i = blockIdx.x * 256 + t;
  int v = counts[i];
  s[t] = v;
  __syncthreads();
  for (int d = 1; d < 256; d <<= 1) {
    int u = (t >= d) ? s[t - d] : 0;
    __syncthreads();
    s[t] += u;
    __syncthreads();
  }
  int ex = boff[blockIdx.x] + s[t] - v;
  off[i] = ex;
  cursor[i] = ex;
  dis[i] = rsqrtf(1.0f + (float)v);
}

// ---------------- scatter edges into CSR (sorted by dst) ------------------
__global__ void k_scatter(const int* __restrict__ src, const int* __restrict__ dst,
                          int* __restrict__ cursor, int* __restrict__ csr_src, int E) {
  int e = blockIdx.x * 256 + threadIdx.x;
  if (e < E) {
    int d = dst[e];
    int p = atomicAdd(&cursor[d], 1);
    csr_src[p] = src[e];
  }
}

// ------- x -> per-row int8 (wave per row; lanes 0..49 hold 8 floats) ------
__global__ __launch_bounds__(256) void k_quantx(const float* __restrict__ x,
                                                int8_t* __restrict__ xq,
                                                float* __restrict__ sx) {
  int wid = threadIdx.x >> 6, lane = threadIdx.x & 63;
  int d = blockIdx.x * 4 + wid;
  float4 v0 = {0.f, 0.f, 0.f, 0.f}, v1 = {0.f, 0.f, 0.f, 0.f};
  if (lane < 50) {
    const float* p = x + (size_t)d * F_IN + lane * 8;
    v0 = *reinterpret_cast<const float4*>(p);
    v1 = *reinterpret_cast<const float4*>(p + 4);
  }
  float m = fmaxf(fmaxf(fmaxf(fabsf(v0.x), fabsf(v0.y)), fmaxf(fabsf(v0.z), fabsf(v0.w))),
                  fmaxf(fmaxf(fabsf(v1.x), fabsf(v1.y)), fmaxf(fabsf(v1.z), fabsf(v1.w))));
#pragma unroll
  for (int o = 32; o; o >>= 1) m = fmaxf(m, __shfl_xor(m, o));
  float inv = (m > 0.f) ? 127.0f / m : 0.f;
  if (lane < 56) {   // 56*8 = 448 bytes (zero pad past 400)
    uint32_t lo = 0, hi = 0;
    if (lane < 50) {
      int q0 = (int)rintf(v0.x * inv), q1 = (int)rintf(v0.y * inv);
      int q2 = (int)rintf(v0.z * inv), q3 = (int)rintf(v0.w * inv);
      int q4 = (int)rintf(v1.x * inv), q5 = (int)rintf(v1.y * inv);
      int q6 = (int)rintf(v1.z * inv), q7 = (int)rintf(v1.w * inv);
      lo = (uint32_t)(q0 & 255) | ((uint32_t)(q1 & 255) << 8) |
           ((uint32_t)(q2 & 255) << 16) | ((uint32_t)(q3 & 255) << 24);
      hi = (uint32_t)(q4 & 255) | ((uint32_t)(q5 & 255) << 8) |
           ((uint32_t)(q6 & 255) << 16) | ((uint32_t)(q7 & 255) << 24);
    }
    uint2 o8; o8.x = lo; o8.y = hi;
    *reinterpret_cast<uint2*>(xq + (size_t)d * K1Q + lane * 8) = o8;
  }
  if (lane == 0) sx[d] = m * (1.0f / 127.0f);
}

// ------- W1 -> per-col int8 [256][448] + sw (wave per col) ----------------
__global__ __launch_bounds__(256) void k_prepw1(const float* __restrict__ W1,
                                                int8_t* __restrict__ w1q,
                                                float* __restrict__ sw) {
  int wid = threadIdx.x >> 6, lane = threadIdx.x & 63;
  int n = blockIdx.x * 4 + wid;
  float vals[7];
  float m = 0.f;
#pragma unroll
  for (int j = 0; j < 7; ++j) {
    int k = lane + j * 64;
    vals[j] = (k < F_IN) ? W1[(size_t)k * H_DIM + n] : 0.f;
    m = fmaxf(m, fabsf(vals[j]));
  }
#pragma unroll
  for (int o = 32; o; o >>= 1) m = fmaxf(m, __shfl_xor(m, o));
  float inv = (m > 0.f) ? 127.0f / m : 0.f;
#pragma unroll
  for (int j = 0; j < 7; ++j) {
    int k = lane + j * 64;
    w1q[(size_t)n * K1Q + k] = (int8_t)(int)rintf(vals[j] * inv);
  }
  if (lane == 0) sw[n] = m * (1.0f / 127.0f);
}

// ------- W2 transpose to bf16 [n][k] --------------------------------------
__global__ __launch_bounds__(256) void k_prepw(const float* __restrict__ W2,
                                               u16* __restrict__ W2T) {
  int k = blockIdx.x, n = threadIdx.x;
  W2T[n * H_DIM + k] = f2bf(W2[k * H_DIM + n]);
}

// ---------------- layer-1 int8 MFMA GEMM: 2-deep counted-vmcnt pipe -------
// C = dis*sx[row]*sw[col]*(Aq @ Bq^T); K=448 (7 stages of 64). LDS geometry
// identical to the bf16 pipe (16B/lane chunks, slot-swizzled both sides).
__global__ __launch_bounds__(256) void k_mmA8(const int8_t* __restrict__ Aq,
                                              const float* __restrict__ sx,
                                              const int8_t* __restrict__ Bq,
                                              const float* __restrict__ sw,
                                              const float* __restrict__ dis,
                                              int8_t* __restrict__ Cq,
                                              float* __restrict__ rs4) {
  constexpr int KB = K1Q, NS = KB >> 6;   // 7
  __shared__ __align__(16) int8_t As[2][64 * 64];
  __shared__ __align__(16) int8_t Bs[2][256 * 64];
  const int tid = threadIdx.x;
  const int lane = tid & 63, wid = tid >> 6;
  const int lr = lane & 15, lg = lane >> 4;
  const int m0 = blockIdx.x * 64;
  // A: lane writes LDS (row=tid>>2, slot=tid&3); source chunk = slot^((row>>1)&3)
  const int aRow = tid >> 2;
  const int aSl = ((tid & 3) ^ ((tid >> 3) & 3)) << 4;      // byte offset
  // B: per j, row=(wid*4+j)*16+(lane>>2), slot=lane&3
  const int bRow16 = lane >> 2;
  const int bSl = ((lane & 3) ^ ((lane >> 3) & 3)) << 4;
  // read slot
  const int rSl = (lg ^ ((lr >> 1) & 3)) << 4;

  auto stage = [&](int s, int b) {
    int k0 = s << 6;
    gl_lds16(Aq + (size_t)(m0 + aRow) * KB + k0 + aSl, (char*)As[b] + wid * 1024);
#pragma unroll
    for (int j = 0; j < 4; ++j) {
      int c = wid * 4 + j;
      gl_lds16(Bq + (size_t)(c * 16 + bRow16) * KB + k0 + bSl, (char*)Bs[b] + c * 1024);
    }
  };

  stage(0, 0);
  stage(1, 1);

  i32x4 acc[4][4] = {};
  for (int k = 0; k < NS; ++k) {
    const int b = k & 1;
    if (k + 1 < NS) wait_vm5(); else wait_vm0();
    __builtin_amdgcn_sched_barrier(0);
    __builtin_amdgcn_s_barrier();
    __builtin_amdgcn_sched_barrier(0);
    i32x4 af[4], bfr[4];
#pragma unroll
    for (int m = 0; m < 4; ++m)
      af[m] = *reinterpret_cast<const i32x4*>(&As[b][(m * 16 + lr) * 64 + rSl]);
#pragma unroll
    for (int n = 0; n < 4; ++n)
      bfr[n] = *reinterpret_cast<const i32x4*>(&Bs[b][(wid * 64 + n * 16 + lr) * 64 + rSl]);
    __builtin_amdgcn_sched_barrier(0);
    wait_lgkm0();
    __builtin_amdgcn_sched_barrier(0);
    __builtin_amdgcn_s_barrier();
    __builtin_amdgcn_sched_barrier(0);
    if (k + 2 < NS) stage(k + 2, b);
    __builtin_amdgcn_sched_barrier(0);
#pragma unroll
    for (int m = 0; m < 4; ++m)
#pragma unroll
      for (int n = 0; n < 4; ++n)
        acc[m][n] = __builtin_amdgcn_mfma_i32_16x16x64_i8(af[m], bfr[n], acc[m][n], 0, 0, 0);
  }

  // ---- epilogue: dequant (sw only; sx cancels in requant) + int8 requant
  float swv[4];
#pragma unroll
  for (int n = 0; n < 4; ++n) swv[n] = sw[wid * 64 + n * 16 + lr];
  float pam[4][4];
#pragma unroll
  for (int m = 0; m < 4; ++m)
#pragma unroll
    for (int r = 0; r < 4; ++r) {
      float v0 = fabsf((float)acc[m][0][r] * swv[0]);
      float v1 = fabsf((float)acc[m][1][r] * swv[1]);
      float v2 = fabsf((float)acc[m][2][r] * swv[2]);
      float v3 = fabsf((float)acc[m][3][r] * swv[3]);
      pam[m][r] = fmaxf(fmaxf(v0, v1), fmaxf(v2, v3));
    }
#pragma unroll
  for (int o = 1; o < 16; o <<= 1)
#pragma unroll
    for (int m = 0; m < 4; ++m)
#pragma unroll
      for (int r = 0; r < 4; ++r)
        pam[m][r] = fmaxf(pam[m][r], __shfl_xor(pam[m][r], o));
#pragma unroll
  for (int m = 0; m < 4; ++m)
#pragma unroll
    for (int r = 0; r < 4; ++r) {
      int grow = m0 + m * 16 + lg * 4 + r;
      float fm = fmaxf(pam[m][r], 1e-20f);
      float inv = 127.0f / fm;
      if (lr == 0) rs4[(size_t)grow * 4 + wid] = dis[grow] * sx[grow] * fm * (1.0f / 127.0f);
#pragma unroll
      for (int n = 0; n < 4; ++n) {
        int q = (int)rintf((float)acc[m][n][r] * swv[n] * inv);
        Cq[(size_t)grow * H_DIM + wid * 64 + n * 16 + lr] = (int8_t)q;
      }
    }
}

// ---------------- layer-2 MFMA GEMM (bf16 A): 2-deep counted-vmcnt pipe ---
template <int KB>
__global__ __launch_bounds__(256) void k_mmB(const u16* __restrict__ A,
                                             const u16* __restrict__ BT,
                                             const float* __restrict__ dis,
                                             int8_t* __restrict__ Cq,
                                             float* __restrict__ rs4) {
  constexpr int NS = KB >> 5;
  __shared__ __align__(16) u16 As[2][64 * 32];
  __shared__ __align__(16) u16 Bs[2][256 * 32];
  const int tid = threadIdx.x;
  const int lane = tid & 63, wid = tid >> 6;
  const int lr = lane & 15, lg = lane >> 4;
  const int m0 = blockIdx.x * 64;
  const int sseg = (((lane & 3) ^ ((lane >> 3) & 3)) << 3);
  const int arow = tid >> 2;
  const int brow = lane >> 2;
  const int rs8 = ((lg ^ ((lr >> 1) & 3)) << 3);

  auto stage = [&](int s, int b) {
    int k0 = s << 5;
    gl_lds16(A + (size_t)(m0 + arow) * KB + k0 + sseg, (char*)As[b] + wid * 1024);
#pragma unroll
    for (int j = 0; j < 4; ++j) {
      int c = wid * 4 + j;
      gl_lds16(BT + (size_t)(c * 16 + brow) * KB + k0 + sseg, (char*)Bs[b] + c * 1024);
    }
  };

  stage(0, 0);
  stage(1, 1);

  f32x4 acc[4][4] = {};
  for (int k = 0; k < NS; ++k) {
    const int b = k & 1;
    if (k + 1 < NS) wait_vm5(); else wait_vm0();
    __builtin_amdgcn_sched_barrier(0);
    __builtin_amdgcn_s_barrier();
    __builtin_amdgcn_sched_barrier(0);
    bf16x8 af[4], bfr[4];
#pragma unroll
    for (int m = 0; m < 4; ++m)
      af[m] = *reinterpret_cast<const bf16x8*>(&As[b][(m * 16 + lr) * 32 + rs8]);
#pragma unroll
    for (int n = 0; n < 4; ++n)
      bfr[n] = *reinterpret_cast<const bf16x8*>(&Bs[b][(wid * 64 + n * 16 + lr) * 32 + rs8]);
    __builtin_amdgcn_sched_barrier(0);
    wait_lgkm0();
    __builtin_amdgcn_sched_barrier(0);
    __builtin_amdgcn_s_barrier();
    __builtin_amdgcn_sched_barrier(0);
    if (k + 2 < NS) stage(k + 2, b);
    __builtin_amdgcn_sched_barrier(0);
#pragma unroll
    for (int m = 0; m < 4; ++m)
#pragma unroll
      for (int n = 0; n < 4; ++n)
        acc[m][n] = __builtin_amdgcn_mfma_f32_16x16x32_bf16(af[m], bfr[n], acc[m][n], 0, 0, 0);
  }

  // ---- epilogue: per-quadrant int8 quantization
  float pam[4][4];
#pragma unroll
  for (int m = 0; m < 4; ++m)
#pragma unroll
    for (int r = 0; r < 4; ++r) {
      float v0 = fabsf(acc[m][0][r]), v1 = fabsf(acc[m][1][r]);
      float v2 = fabsf(acc[m][2][r]), v3 = fabsf(acc[m][3][r]);
      pam[m][r] = fmaxf(fmaxf(v0, v1), fmaxf(v2, v3));
    }
#pragma unroll
  for (int o = 1; o < 16; o <<= 1)
#pragma unroll
    for (int m = 0; m < 4; ++m)
#pragma unroll
      for (int r = 0; r < 4; ++r)
        pam[m][r] = fmaxf(pam[m][r], __shfl_xor(pam[m][r], o));
#pragma unroll
  for (int m = 0; m < 4; ++m)
#pragma unroll
    for (int r = 0; r < 4; ++r) {
      int grow = m0 + m * 16 + lg * 4 + r;
      float fm = fmaxf(pam[m][r], 1e-20f);
      float inv = 127.0f / fm;
      if (lr == 0) rs4[(size_t)grow * 4 + wid] = dis[grow] * fm * (1.0f / 127.0f);
#pragma unroll
      for (int n = 0; n < 4; ++n) {
        int q = (int)rintf(acc[m][n][r] * inv);
        Cq[(size_t)grow * H_DIM + wid * 64 + n * 16 + lr] = (int8_t)q;
      }
    }
}

// ------- int8 gather group: U independent row loads + quadrant scales -----
template <int U>
__device__ __forceinline__ void gath8(const int8_t* __restrict__ tq,
                                      const float* __restrict__ rs4,
                                      const int* __restrict__ csr, int e,
                                      int f0, int qo,
                                      float& a0, float& a1, float& a2, float& a3) {
  int s[U];
  uint32_t v[U];
  float sc[U];
#pragma unroll
  for (int i = 0; i < U; ++i) s[i] = csr[e + i];
#pragma unroll
  for (int i = 0; i < U; ++i) {
    v[i] = *reinterpret_cast<const uint32_t*>(tq + ((size_t)s[i] << 8) + f0);
    sc[i] = rs4[((size_t)s[i] << 2) + qo];
  }
#pragma unroll
  for (int i = 0; i < U; ++i) {
    a0 += sc[i] * (float)(int8_t)(v[i]);
    a1 += sc[i] * (float)(int8_t)(v[i] >> 8);
    a2 += sc[i] * (float)(int8_t)(v[i] >> 16);
    a3 += sc[i] * (float)(int8_t)(v[i] >> 24);
  }
}

// ------- aggregation on quantized pre-scaled rows ------------------------
template <bool FUSE_T3>
__global__ __launch_bounds__(256) void k_agg(const int8_t* __restrict__ tq,
                                             const float* __restrict__ rs4,
                                             const int* __restrict__ off,
                                             const int* __restrict__ csr,
                                             const float* __restrict__ dis,
                                             const float* __restrict__ bias,
                                             u16* __restrict__ h,
                                             const float* __restrict__ W3,
                                             float* __restrict__ t3, int N) {
  int wid = threadIdx.x >> 6, lane = threadIdx.x & 63;
  int d = blockIdx.x * 4 + wid;
  if (d >= N) return;
  int f0 = lane * 4;
  int qo = lane >> 4;
  float a0, a1, a2, a3;
  {
    uint32_t v = *reinterpret_cast<const uint32_t*>(tq + ((size_t)d << 8) + f0);
    float sc = rs4[((size_t)d << 2) + qo];
    a0 = sc * (float)(int8_t)(v);
    a1 = sc * (float)(int8_t)(v >> 8);
    a2 = sc * (float)(int8_t)(v >> 16);
    a3 = sc * (float)(int8_t)(v >> 24);
  }
  int e = off[d], e1 = off[d + 1];
  while (e + 8 <= e1) { gath8<8>(tq, rs4, csr, e, f0, qo, a0, a1, a2, a3); e += 8; }
  if (e + 4 <= e1) { gath8<4>(tq, rs4, csr, e, f0, qo, a0, a1, a2, a3); e += 4; }
  if (e + 2 <= e1) { gath8<2>(tq, rs4, csr, e, f0, qo, a0, a1, a2, a3); e += 2; }
  if (e < e1)      { gath8<1>(tq, rs4, csr, e, f0, qo, a0, a1, a2, a3); }
  float dd = dis[d];
  float4 bv = *reinterpret_cast<const float4*>(bias + f0);
  float r0 = fmaxf(dd * a0 + bv.x, 0.f);
  float r1 = fmaxf(dd * a1 + bv.y, 0.f);
  float r2 = fmaxf(dd * a2 + bv.z, 0.f);
  float r3 = fmaxf(dd * a3 + bv.w, 0.f);
  if (FUSE_T3) {
    float p0 = r0 * W3[(f0 + 0) * 2]     + r1 * W3[(f0 + 1) * 2]
             + r2 * W3[(f0 + 2) * 2]     + r3 * W3[(f0 + 3) * 2];
    float p1 = r0 * W3[(f0 + 0) * 2 + 1] + r1 * W3[(f0 + 1) * 2 + 1]
             + r2 * W3[(f0 + 2) * 2 + 1] + r3 * W3[(f0 + 3) * 2 + 1];
#pragma unroll
    for (int o = 32; o; o >>= 1) { p0 += __shfl_xor(p0, o); p1 += __shfl_xor(p1, o); }
    if (lane == 0) {
      t3[d * 2] = dd * p0;
      t3[d * 2 + 1] = dd * p1;
    }
  } else {
    ushort4 o;
    o.x = f2bf(r0); o.y = f2bf(r1); o.z = f2bf(r2); o.w = f2bf(r3);
    *reinterpret_cast<ushort4*>(h + ((size_t)d << 8) + f0) = o;
  }
}

// ------ fused layer-3 aggregation + mean pool: one block per graph --------
__global__ __launch_bounds__(448) void k_aggpool3(const float* __restrict__ t3,
                                                  const int* __restrict__ off,
                                                  const int* __restrict__ csr,
                                                  const float* __restrict__ dis,
                                                  const float* __restrict__ b3,
                                                  float* __restrict__ out) {
  int g = blockIdx.x, t = threadIdx.x;
  int lane = t & 63, wv = t >> 6;
  float a0 = 0.f, a1 = 0.f;
  if (t < NODES_PER_GRAPH) {
    int d = g * NODES_PER_GRAPH + t;
    a0 = t3[d * 2]; a1 = t3[d * 2 + 1];
    int e = off[d], e1 = off[d + 1];
    while (e + 4 <= e1) {
      int s0 = csr[e], s1 = csr[e + 1], s2 = csr[e + 2], s3 = csr[e + 3];
      float2 v0 = *reinterpret_cast<const float2*>(t3 + s0 * 2);
      float2 v1 = *reinterpret_cast<const float2*>(t3 + s1 * 2);
      float2 v2 = *reinterpret_cast<const float2*>(t3 + s2 * 2);
      float2 v3 = *reinterpret_cast<const float2*>(t3 + s3 * 2);
      a0 += v0.x + v1.x + v2.x + v3.x;
      a1 += v0.y + v1.y + v2.y + v3.y;
      e += 4;
    }
    while (e < e1) {
      float2 v = *reinterpret_cast<const float2*>(t3 + csr[e] * 2);
      a0 += v.x; a1 += v.y; ++e;
    }
    float dd = dis[d];
    a0 *= dd; a1 *= dd;
  }
#pragma unroll
  for (int o = 32; o; o >>= 1) { a0 += __shfl_xor(a0, o); a1 += __shfl_xor(a1, o); }
  __shared__ float w0[8], w1[8];
  if (lane == 0) { w0[wv] = a0; w1[wv] = a1; }
  __syncthreads();
  if (t == 0) {
    float s0 = 0.f, s1 = 0.f;
#pragma unroll
    for (int i = 0; i < 7; ++i) { s0 += w0[i]; s1 += w1[i]; }
    out[g * 2]     = s0 * (1.0f / NODES_PER_GRAPH) + b3[0];
    out[g * 2 + 1] = s1 * (1.0f / NODES_PER_GRAPH) + b3[1];
  }
}

extern "C" void kernel_launch(void* const* d_in, const int* in_sizes, int n_in,
                              void* d_out, int out_size, void* d_ws, size_t ws_size,
                              hipStream_t stream) {
  const float* x  = (const float*)d_in[0];
  const int*   ei = (const int*)d_in[1];
  const float* W1 = (const float*)d_in[2];
  const float* b1 = (const float*)d_in[3];
  const float* W2 = (const float*)d_in[4];
  const float* b2 = (const float*)d_in[5];
  const float* W3 = (const float*)d_in[6];
  const float* b3 = (const float*)d_in[7];
  float* out = (float*)d_out;
  const int N = N_NODES, E = N_EDGES;
  const int* src = ei;
  const int* dst = ei + E;

  char* ws = (char*)d_ws;
  size_t o = 0;
  auto alloc = [&](size_t bytes) -> void* {
    void* p = ws + o;
    o += (bytes + 255) & ~(size_t)255;
    return p;
  };
  int8_t* tQ  = (int8_t*)alloc((size_t)N * H_DIM);
  float* rs4  = (float*)alloc((size_t)N * 4 * 4);
  u16* tB     = (u16*)alloc((size_t)N * H_DIM * 2);
  u16* W2T    = (u16*)alloc((size_t)H_DIM * H_DIM * 2);
  float* dis  = (float*)alloc((size_t)N * 4);
  int* counts = (int*)alloc((size_t)N * 4);
  int* cursor = (int*)alloc((size_t)N * 4);
  int* csroff = (int*)alloc((size_t)(N + 1) * 4);
  int* csr    = (int*)alloc((size_t)E * 4);
  float* t3   = (float*)alloc((size_t)N * 2 * 4);
  int* bsum   = (int*)alloc((size_t)NB_SCAN * 4);
  int* boff   = (int*)alloc((size_t)NB_SCAN * 4);
  int8_t* xq  = (int8_t*)alloc((size_t)N * K1Q);
  float* sx   = (float*)alloc((size_t)N * 4);
  int8_t* w1q = (int8_t*)alloc((size_t)H_DIM * K1Q);
  float* sw   = (float*)alloc((size_t)H_DIM * 4);

  hipMemsetAsync(counts, 0, (size_t)N * 4, stream);
  k_hist<<<(E + 255) / 256, 256, 0, stream>>>(dst, counts, E);
  k_reduce<<<NB_SCAN, 256, 0, stream>>>(counts, bsum);
  k_scantop<<<1, 256, 0, stream>>>(bsum, boff, csroff + N);
  k_scanlocal<<<NB_SCAN, 256, 0, stream>>>(counts, boff, csroff, cursor, dis);
  k_scatter<<<(E + 255) / 256, 256, 0, stream>>>(src, dst, cursor, csr, E);
  k_quantx<<<N / 4, 256, 0, stream>>>(x, xq, sx);
  k_prepw1<<<H_DIM / 4, 256, 0, stream>>>(W1, w1q, sw);
  k_prepw<<<H_DIM, 256, 0, stream>>>(W2, W2T);

  // layer 1 (int8 MFMA)
  k_mmA8<<<N / 64, 256, 0, stream>>>(xq, sx, w1q, sw, dis, tQ, rs4);
  k_agg<false><<<N / 4, 256, 0, stream>>>(tQ, rs4, csroff, csr, dis, b1, tB, nullptr, nullptr, N);
  // layer 2 (agg fused with layer-3 matmul -> t3)
  k_mmB<H_DIM><<<N / 64, 256, 0, stream>>>(tB, W2T, dis, tQ, rs4);
  k_agg<true><<<N / 4, 256, 0, stream>>>(tQ, rs4, csroff, csr, dis, b2, nullptr, W3, t3, N);
  // layer 3 aggregation fused with mean pool
  k_aggpool3<<<N_GRAPHS, 448, 0, stream>>>(t3, csroff, csr, dis, b3, out);
}

// Round 11
// 225.825 us; speedup vs baseline: 1.2026x; 1.2026x over previous
//
#include <hip/hip_runtime.h>
#include <hip/hip_bf16.h>
#include <stdint.h>

typedef __attribute__((ext_vector_type(8))) __bf16 bf16x8;
typedef __attribute__((ext_vector_type(4))) float f32x4;
typedef __attribute__((ext_vector_type(4))) int i32x4;
typedef unsigned short u16;

#define N_NODES 51200
#define N_EDGES 819200
#define F_IN 400
#define K1Q 448
#define H_DIM 256
#define C_OUT 2
#define N_GRAPHS 128
#define NODES_PER_GRAPH 400
#define NB_SCAN (N_NODES / 256)   // 200 blocks

__device__ __forceinline__ u16 f2bf(float f) {
  uint32_t u = __builtin_bit_cast(uint32_t, f);
  u = (u + 0x7fffu + ((u >> 16) & 1u)) >> 16;
  return (u16)u;
}
__device__ __forceinline__ float bf2f(u16 s) {
  uint32_t u = ((uint32_t)s) << 16;
  return __builtin_bit_cast(float, u);
}

typedef const __attribute__((address_space(1))) unsigned int* gas_ptr;
typedef __attribute__((address_space(3))) unsigned int* las_ptr;
__device__ __forceinline__ void gl_lds16(const void* g, void* l) {
  __builtin_amdgcn_global_load_lds((gas_ptr)g, (las_ptr)l, 16, 0, 0);
}
__device__ __forceinline__ void wait_vm0()   { asm volatile("s_waitcnt vmcnt(0)" ::: "memory"); }
__device__ __forceinline__ void wait_vm5()   { asm volatile("s_waitcnt vmcnt(5)" ::: "memory"); }
__device__ __forceinline__ void wait_lgkm0() { asm volatile("s_waitcnt lgkmcnt(0)" ::: "memory"); }

// ------ merged histogram + rank handout: rank[e] = old count of dst[e] -----
__global__ void k_histrank(const int* __restrict__ dst, int* __restrict__ counts,
                           int* __restrict__ rank, int E) {
  int e = blockIdx.x * 256 + threadIdx.x;
  if (e < E) rank[e] = atomicAdd(&counts[dst[e]], 1);
}

// ---------------- hierarchical scan: phase 1, per-block sums --------------
__global__ __launch_bounds__(256) void k_reduce(const int* __restrict__ counts,
                                                int* __restrict__ bsum) {
  int i = blockIdx.x * 256 + threadIdx.x;
  int v = counts[i];
#pragma unroll
  for (int o = 32; o; o >>= 1) v += __shfl_xor(v, o);
  __shared__ int wsum[4];
  if ((threadIdx.x & 63) == 0) wsum[threadIdx.x >> 6] = v;
  __syncthreads();
  if (threadIdx.x == 0) bsum[blockIdx.x] = wsum[0] + wsum[1] + wsum[2] + wsum[3];
}

// ---------------- phase 2: scan the 200 block sums (one small block) ------
__global__ __launch_bounds__(256) void k_scantop(const int* __restrict__ bsum,
                                                 int* __restrict__ boff,
                                                 int* __restrict__ off_last) {
  __shared__ int s[256];
  int t = threadIdx.x;
  int v = (t < NB_SCAN) ? bsum[t] : 0;
  s[t] = v;
  __syncthreads();
  for (int d = 1; d < 256; d <<= 1) {
    int u = (t >= d) ? s[t - d] : 0;
    __syncthreads();
    s[t] += u;
    __syncthreads();
  }
  if (t < NB_SCAN) boff[t] = s[t] - v;   // exclusive prefix of block sums
  if (t == 0) *off_last = N_EDGES;       // off[N] = total edges
}

// ---------------- phase 3: local scan + block offset; also dis ------------
__global__ __launch_bounds__(256) void k_scanlocal(const int* __restrict__ counts,
                                                   const int* __restrict__ boff,
                                                   int* __restrict__ off,
                                                   float* __restrict__ dis) {
  __shared__ int s[256];
  int t = threadIdx.x;
  int i = blockIdx.x * 256 + t;
  int v = counts[i];
  s[t] = v;
  __syncthreads();
  for (int d = 1; d < 256; d <<= 1) {
    int u = (t >= d) ? s[t - d] : 0;
    __syncthreads();
    s[t] += u;
    __syncthreads();
  }
  int ex = boff[blockIdx.x] + s[t] - v;
  off[i] = ex;
  dis[i] = rsqrtf(1.0f + (float)v);
}

// --------- atomic-free placement: csr[off[d] + rank[e]] = src[e] ----------
__global__ void k_place(const int* __restrict__ src, const int* __restrict__ dst,
                        const int* __restrict__ rank, const int* __restrict__ off,
                        int* __restrict__ csr_src, int E) {
  int e = blockIdx.x * 256 + threadIdx.x;
  if (e < E) {
    int d = dst[e];
    csr_src[off[d] + rank[e]] = src[e];
  }
}

// ------- x -> per-row int8 (wave per row; lanes 0..49 hold 8 floats) ------
__global__ __launch_bounds__(256) void k_quantx(const float* __restrict__ x,
                                                int8_t* __restrict__ xq,
                                                float* __restrict__ sx) {
  int wid = threadIdx.x >> 6, lane = threadIdx.x & 63;
  int d = blockIdx.x * 4 + wid;
  float4 v0 = {0.f, 0.f, 0.f, 0.f}, v1 = {0.f, 0.f, 0.f, 0.f};
  if (lane < 50) {
    const float* p = x + (size_t)d * F_IN + lane * 8;
    v0 = *reinterpret_cast<const float4*>(p);
    v1 = *reinterpret_cast<const float4*>(p + 4);
  }
  float m = fmaxf(fmaxf(fmaxf(fabsf(v0.x), fabsf(v0.y)), fmaxf(fabsf(v0.z), fabsf(v0.w))),
                  fmaxf(fmaxf(fabsf(v1.x), fabsf(v1.y)), fmaxf(fabsf(v1.z), fabsf(v1.w))));
#pragma unroll
  for (int o = 32; o; o >>= 1) m = fmaxf(m, __shfl_xor(m, o));
  float inv = (m > 0.f) ? 127.0f / m : 0.f;
  if (lane < 56) {   // 56*8 = 448 bytes (zero pad past 400)
    uint32_t lo = 0, hi = 0;
    if (lane < 50) {
      int q0 = (int)rintf(v0.x * inv), q1 = (int)rintf(v0.y * inv);
      int q2 = (int)rintf(v0.z * inv), q3 = (int)rintf(v0.w * inv);
      int q4 = (int)rintf(v1.x * inv), q5 = (int)rintf(v1.y * inv);
      int q6 = (int)rintf(v1.z * inv), q7 = (int)rintf(v1.w * inv);
      lo = (uint32_t)(q0 & 255) | ((uint32_t)(q1 & 255) << 8) |
           ((uint32_t)(q2 & 255) << 16) | ((uint32_t)(q3 & 255) << 24);
      hi = (uint32_t)(q4 & 255) | ((uint32_t)(q5 & 255) << 8) |
           ((uint32_t)(q6 & 255) << 16) | ((uint32_t)(q7 & 255) << 24);
    }
    uint2 o8; o8.x = lo; o8.y = hi;
    *reinterpret_cast<uint2*>(xq + (size_t)d * K1Q + lane * 8) = o8;
  }
  if (lane == 0) sx[d] = m * (1.0f / 127.0f);
}

// ------- fused weight prep: blocks [0,64) -> W1 int8; [64,320) -> W2 bf16 -
__global__ __launch_bounds__(256) void k_prepw(const float* __restrict__ W1,
                                               const float* __restrict__ W2,
                                               int8_t* __restrict__ w1q,
                                               float* __restrict__ sw,
                                               u16* __restrict__ W2T) {
  int b = blockIdx.x;
  if (b < H_DIM / 4) {
    int wid = threadIdx.x >> 6, lane = threadIdx.x & 63;
    int n = b * 4 + wid;
    float vals[7];
    float m = 0.f;
#pragma unroll
    for (int j = 0; j < 7; ++j) {
      int k = lane + j * 64;
      vals[j] = (k < F_IN) ? W1[(size_t)k * H_DIM + n] : 0.f;
      m = fmaxf(m, fabsf(vals[j]));
    }
#pragma unroll
    for (int o = 32; o; o >>= 1) m = fmaxf(m, __shfl_xor(m, o));
    float inv = (m > 0.f) ? 127.0f / m : 0.f;
#pragma unroll
    for (int j = 0; j < 7; ++j) {
      int k = lane + j * 64;
      w1q[(size_t)n * K1Q + k] = (int8_t)(int)rintf(vals[j] * inv);
    }
    if (lane == 0) sw[n] = m * (1.0f / 127.0f);
  } else {
    int k = b - H_DIM / 4, n = threadIdx.x;
    W2T[n * H_DIM + k] = f2bf(W2[k * H_DIM + n]);
  }
}

// ---------------- layer-1 int8 MFMA GEMM: 2-deep counted-vmcnt pipe -------
__global__ __launch_bounds__(256) void k_mmA8(const int8_t* __restrict__ Aq,
                                              const float* __restrict__ sx,
                                              const int8_t* __restrict__ Bq,
                                              const float* __restrict__ sw,
                                              const float* __restrict__ dis,
                                              int8_t* __restrict__ Cq,
                                              float* __restrict__ rs4) {
  constexpr int KB = K1Q, NS = KB >> 6;   // 7
  __shared__ __align__(16) int8_t As[2][64 * 64];
  __shared__ __align__(16) int8_t Bs[2][256 * 64];
  const int tid = threadIdx.x;
  const int lane = tid & 63, wid = tid >> 6;
  const int lr = lane & 15, lg = lane >> 4;
  const int m0 = blockIdx.x * 64;
  const int aRow = tid >> 2;
  const int aSl = ((tid & 3) ^ ((tid >> 3) & 3)) << 4;
  const int bRow16 = lane >> 2;
  const int bSl = ((lane & 3) ^ ((lane >> 3) & 3)) << 4;
  const int rSl = (lg ^ ((lr >> 1) & 3)) << 4;

  auto stage = [&](int s, int b) {
    int k0 = s << 6;
    gl_lds16(Aq + (size_t)(m0 + aRow) * KB + k0 + aSl, (char*)As[b] + wid * 1024);
#pragma unroll
    for (int j = 0; j < 4; ++j) {
      int c = wid * 4 + j;
      gl_lds16(Bq + (size_t)(c * 16 + bRow16) * KB + k0 + bSl, (char*)Bs[b] + c * 1024);
    }
  };

  stage(0, 0);
  stage(1, 1);

  i32x4 acc[4][4] = {};
  for (int k = 0; k < NS; ++k) {
    const int b = k & 1;
    if (k + 1 < NS) wait_vm5(); else wait_vm0();
    __builtin_amdgcn_sched_barrier(0);
    __builtin_amdgcn_s_barrier();
    __builtin_amdgcn_sched_barrier(0);
    i32x4 af[4], bfr[4];
#pragma unroll
    for (int m = 0; m < 4; ++m)
      af[m] = *reinterpret_cast<const i32x4*>(&As[b][(m * 16 + lr) * 64 + rSl]);
#pragma unroll
    for (int n = 0; n < 4; ++n)
      bfr[n] = *reinterpret_cast<const i32x4*>(&Bs[b][(wid * 64 + n * 16 + lr) * 64 + rSl]);
    __builtin_amdgcn_sched_barrier(0);
    wait_lgkm0();
    __builtin_amdgcn_sched_barrier(0);
    __builtin_amdgcn_s_barrier();
    __builtin_amdgcn_sched_barrier(0);
    if (k + 2 < NS) stage(k + 2, b);
    __builtin_amdgcn_sched_barrier(0);
#pragma unroll
    for (int m = 0; m < 4; ++m)
#pragma unroll
      for (int n = 0; n < 4; ++n)
        acc[m][n] = __builtin_amdgcn_mfma_i32_16x16x64_i8(af[m], bfr[n], acc[m][n], 0, 0, 0);
  }

  // ---- epilogue: dequant (sw only; sx cancels in requant) + int8 requant
  float swv[4];
#pragma unroll
  for (int n = 0; n < 4; ++n) swv[n] = sw[wid * 64 + n * 16 + lr];
  float pam[4][4];
#pragma unroll
  for (int m = 0; m < 4; ++m)
#pragma unroll
    for (int r = 0; r < 4; ++r) {
      float v0 = fabsf((float)acc[m][0][r] * swv[0]);
      float v1 = fabsf((float)acc[m][1][r] * swv[1]);
      float v2 = fabsf((float)acc[m][2][r] * swv[2]);
      float v3 = fabsf((float)acc[m][3][r] * swv[3]);
      pam[m][r] = fmaxf(fmaxf(v0, v1), fmaxf(v2, v3));
    }
#pragma unroll
  for (int o = 1; o < 16; o <<= 1)
#pragma unroll
    for (int m = 0; m < 4; ++m)
#pragma unroll
      for (int r = 0; r < 4; ++r)
        pam[m][r] = fmaxf(pam[m][r], __shfl_xor(pam[m][r], o));
#pragma unroll
  for (int m = 0; m < 4; ++m)
#pragma unroll
    for (int r = 0; r < 4; ++r) {
      int grow = m0 + m * 16 + lg * 4 + r;
      float fm = fmaxf(pam[m][r], 1e-20f);
      float inv = 127.0f / fm;
      if (lr == 0) rs4[(size_t)grow * 4 + wid] = dis[grow] * sx[grow] * fm * (1.0f / 127.0f);
#pragma unroll
      for (int n = 0; n < 4; ++n) {
        int q = (int)rintf((float)acc[m][n][r] * swv[n] * inv);
        Cq[(size_t)grow * H_DIM + wid * 64 + n * 16 + lr] = (int8_t)q;
      }
    }
}

// ---------------- layer-2 MFMA GEMM (bf16 A): 2-deep counted-vmcnt pipe ---
template <int KB>
__global__ __launch_bounds__(256) void k_mmB(const u16* __restrict__ A,
                                             const u16* __restrict__ BT,
                                             const float* __restrict__ dis,
                                             int8_t* __restrict__ Cq,
                                             float* __restrict__ rs4) {
  constexpr int NS = KB >> 5;
  __shared__ __align__(16) u16 As[2][64 * 32];
  __shared__ __align__(16) u16 Bs[2][256 * 32];
  const int tid = threadIdx.x;
  const int lane = tid & 63, wid = tid >> 6;
  const int lr = lane & 15, lg = lane >> 4;
  const int m0 = blockIdx.x * 64;
  const int sseg = (((lane & 3) ^ ((lane >> 3) & 3)) << 3);
  const int arow = tid >> 2;
  const int brow = lane >> 2;
  const int rs8 = ((lg ^ ((lr >> 1) & 3)) << 3);

  auto stage = [&](int s, int b) {
    int k0 = s << 5;
    gl_lds16(A + (size_t)(m0 + arow) * KB + k0 + sseg, (char*)As[b] + wid * 1024);
#pragma unroll
    for (int j = 0; j < 4; ++j) {
      int c = wid * 4 + j;
      gl_lds16(BT + (size_t)(c * 16 + brow) * KB + k0 + sseg, (char*)Bs[b] + c * 1024);
    }
  };

  stage(0, 0);
  stage(1, 1);

  f32x4 acc[4][4] = {};
  for (int k = 0; k < NS; ++k) {
    const int b = k & 1;
    if (k + 1 < NS) wait_vm5(); else wait_vm0();
    __builtin_amdgcn_sched_barrier(0);
    __builtin_amdgcn_s_barrier();
    __builtin_amdgcn_sched_barrier(0);
    bf16x8 af[4], bfr[4];
#pragma unroll
    for (int m = 0; m < 4; ++m)
      af[m] = *reinterpret_cast<const bf16x8*>(&As[b][(m * 16 + lr) * 32 + rs8]);
#pragma unroll
    for (int n = 0; n < 4; ++n)
      bfr[n] = *reinterpret_cast<const bf16x8*>(&Bs[b][(wid * 64 + n * 16 + lr) * 32 + rs8]);
    __builtin_amdgcn_sched_barrier(0);
    wait_lgkm0();
    __builtin_amdgcn_sched_barrier(0);
    __builtin_amdgcn_s_barrier();
    __builtin_amdgcn_sched_barrier(0);
    if (k + 2 < NS) stage(k + 2, b);
    __builtin_amdgcn_sched_barrier(0);
#pragma unroll
    for (int m = 0; m < 4; ++m)
#pragma unroll
      for (int n = 0; n < 4; ++n)
        acc[m][n] = __builtin_amdgcn_mfma_f32_16x16x32_bf16(af[m], bfr[n], acc[m][n], 0, 0, 0);
  }

  // ---- epilogue: per-quadrant int8 quantization
  float pam[4][4];
#pragma unroll
  for (int m = 0; m < 4; ++m)
#pragma unroll
    for (int r = 0; r < 4; ++r) {
      float v0 = fabsf(acc[m][0][r]), v1 = fabsf(acc[m][1][r]);
      float v2 = fabsf(acc[m][2][r]), v3 = fabsf(acc[m][3][r]);
      pam[m][r] = fmaxf(fmaxf(v0, v1), fmaxf(v2, v3));
    }
#pragma unroll
  for (int o = 1; o < 16; o <<= 1)
#pragma unroll
    for (int m = 0; m < 4; ++m)
#pragma unroll
      for (int r = 0; r < 4; ++r)
        pam[m][r] = fmaxf(pam[m][r], __shfl_xor(pam[m][r], o));
#pragma unroll
  for (int m = 0; m < 4; ++m)
#pragma unroll
    for (int r = 0; r < 4; ++r) {
      int grow = m0 + m * 16 + lg * 4 + r;
      float fm = fmaxf(pam[m][r], 1e-20f);
      float inv = 127.0f / fm;
      if (lr == 0) rs4[(size_t)grow * 4 + wid] = dis[grow] * fm * (1.0f / 127.0f);
#pragma unroll
      for (int n = 0; n < 4; ++n) {
        int q = (int)rintf(acc[m][n][r] * inv);
        Cq[(size_t)grow * H_DIM + wid * 64 + n * 16 + lr] = (int8_t)q;
      }
    }
}

// ------- int8 gather group: U independent row loads + quadrant scales -----
template <int U>
__device__ __forceinline__ void gath8(const int8_t* __restrict__ tq,
                                      const float* __restrict__ rs4,
                                      const int* __restrict__ csr, int e,
                                      int f0, int qo,
                                      float& a0, float& a1, float& a2, float& a3) {
  int s[U];
  uint32_t v[U];
  float sc[U];
#pragma unroll
  for (int i = 0; i < U; ++i) s[i] = csr[e + i];
#pragma unroll
  for (int i = 0; i < U; ++i) {
    v[i] = *reinterpret_cast<const uint32_t*>(tq + ((size_t)s[i] << 8) + f0);
    sc[i] = rs4[((size_t)s[i] << 2) + qo];
  }
#pragma unroll
  for (int i = 0; i < U; ++i) {
    a0 += sc[i] * (float)(int8_t)(v[i]);
    a1 += sc[i] * (float)(int8_t)(v[i] >> 8);
    a2 += sc[i] * (float)(int8_t)(v[i] >> 16);
    a3 += sc[i] * (float)(int8_t)(v[i] >> 24);
  }
}

// ------- aggregation on quantized pre-scaled rows ------------------------
template <bool FUSE_T3>
__global__ __launch_bounds__(256) void k_agg(const int8_t* __restrict__ tq,
                                             const float* __restrict__ rs4,
                                             const int* __restrict__ off,
                                             const int* __restrict__ csr,
                                             const float* __restrict__ dis,
                                             const float* __restrict__ bias,
                                             u16* __restrict__ h,
                                             const float* __restrict__ W3,
                                             float* __restrict__ t3, int N) {
  int wid = threadIdx.x >> 6, lane = threadIdx.x & 63;
  int d = blockIdx.x * 4 + wid;
  if (d >= N) return;
  int f0 = lane * 4;
  int qo = lane >> 4;
  float a0, a1, a2, a3;
  {
    uint32_t v = *reinterpret_cast<const uint32_t*>(tq + ((size_t)d << 8) + f0);
    float sc = rs4[((size_t)d << 2) + qo];
    a0 = sc * (float)(int8_t)(v);
    a1 = sc * (float)(int8_t)(v >> 8);
    a2 = sc * (float)(int8_t)(v >> 16);
    a3 = sc * (float)(int8_t)(v >> 24);
  }
  int e = off[d], e1 = off[d + 1];
  while (e + 8 <= e1) { gath8<8>(tq, rs4, csr, e, f0, qo, a0, a1, a2, a3); e += 8; }
  if (e + 4 <= e1) { gath8<4>(tq, rs4, csr, e, f0, qo, a0, a1, a2, a3); e += 4; }
  if (e + 2 <= e1) { gath8<2>(tq, rs4, csr, e, f0, qo, a0, a1, a2, a3); e += 2; }
  if (e < e1)      { gath8<1>(tq, rs4, csr, e, f0, qo, a0, a1, a2, a3); }
  float dd = dis[d];
  float4 bv = *reinterpret_cast<const float4*>(bias + f0);
  float r0 = fmaxf(dd * a0 + bv.x, 0.f);
  float r1 = fmaxf(dd * a1 + bv.y, 0.f);
  float r2 = fmaxf(dd * a2 + bv.z, 0.f);
  float r3 = fmaxf(dd * a3 + bv.w, 0.f);
  if (FUSE_T3) {
    float p0 = r0 * W3[(f0 + 0) * 2]     + r1 * W3[(f0 + 1) * 2]
             + r2 * W3[(f0 + 2) * 2]     + r3 * W3[(f0 + 3) * 2];
    float p1 = r0 * W3[(f0 + 0) * 2 + 1] + r1 * W3[(f0 + 1) * 2 + 1]
             + r2 * W3[(f0 + 2) * 2 + 1] + r3 * W3[(f0 + 3) * 2 + 1];
#pragma unroll
    for (int o = 32; o; o >>= 1) { p0 += __shfl_xor(p0, o); p1 += __shfl_xor(p1, o); }
    if (lane == 0) {
      t3[d * 2] = dd * p0;
      t3[d * 2 + 1] = dd * p1;
    }
  } else {
    ushort4 o;
    o.x = f2bf(r0); o.y = f2bf(r1); o.z = f2bf(r2); o.w = f2bf(r3);
    *reinterpret_cast<ushort4*>(h + ((size_t)d << 8) + f0) = o;
  }
}

// ------ fused layer-3 aggregation + mean pool: one block per graph --------
__global__ __launch_bounds__(448) void k_aggpool3(const float* __restrict__ t3,
                                                  const int* __restrict__ off,
                                                  const int* __restrict__ csr,
                                                  const float* __restrict__ dis,
                                                  const float* __restrict__ b3,
                                                  float* __restrict__ out) {
  int g = blockIdx.x, t = threadIdx.x;
  int lane = t & 63, wv = t >> 6;
  float a0 = 0.f, a1 = 0.f;
  if (t < NODES_PER_GRAPH) {
    int d = g * NODES_PER_GRAPH + t;
    a0 = t3[d * 2]; a1 = t3[d * 2 + 1];
    int e = off[d], e1 = off[d + 1];
    while (e + 4 <= e1) {
      int s0 = csr[e], s1 = csr[e + 1], s2 = csr[e + 2], s3 = csr[e + 3];
      float2 v0 = *reinterpret_cast<const float2*>(t3 + s0 * 2);
      float2 v1 = *reinterpret_cast<const float2*>(t3 + s1 * 2);
      float2 v2 = *reinterpret_cast<const float2*>(t3 + s2 * 2);
      float2 v3 = *reinterpret_cast<const float2*>(t3 + s3 * 2);
      a0 += v0.x + v1.x + v2.x + v3.x;
      a1 += v0.y + v1.y + v2.y + v3.y;
      e += 4;
    }
    while (e < e1) {
      float2 v = *reinterpret_cast<const float2*>(t3 + csr[e] * 2);
      a0 += v.x; a1 += v.y; ++e;
    }
    float dd = dis[d];
    a0 *= dd; a1 *= dd;
  }
#pragma unroll
  for (int o = 32; o; o >>= 1) { a0 += __shfl_xor(a0, o); a1 += __shfl_xor(a1, o); }
  __shared__ float w0[8], w1[8];
  if (lane == 0) { w0[wv] = a0; w1[wv] = a1; }
  __syncthreads();
  if (t == 0) {
    float s0 = 0.f, s1 = 0.f;
#pragma unroll
    for (int i = 0; i < 7; ++i) { s0 += w0[i]; s1 += w1[i]; }
    out[g * 2]     = s0 * (1.0f / NODES_PER_GRAPH) + b3[0];
    out[g * 2 + 1] = s1 * (1.0f / NODES_PER_GRAPH) + b3[1];
  }
}

extern "C" void kernel_launch(void* const* d_in, const int* in_sizes, int n_in,
                              void* d_out, int out_size, void* d_ws, size_t ws_size,
                              hipStream_t stream) {
  const float* x  = (const float*)d_in[0];
  const int*   ei = (const int*)d_in[1];
  const float* W1 = (const float*)d_in[2];
  const float* b1 = (const float*)d_in[3];
  const float* W2 = (const float*)d_in[4];
  const float* b2 = (const float*)d_in[5];
  const float* W3 = (const float*)d_in[6];
  const float* b3 = (const float*)d_in[7];
  float* out = (float*)d_out;
  const int N = N_NODES, E = N_EDGES;
  const int* src = ei;
  const int* dst = ei + E;

  char* ws = (char*)d_ws;
  size_t o = 0;
  auto alloc = [&](size_t bytes) -> void* {
    void* p = ws + o;
    o += (bytes + 255) & ~(size_t)255;
    return p;
  };
  int8_t* tQ  = (int8_t*)alloc((size_t)N * H_DIM);
  float* rs4  = (float*)alloc((size_t)N * 4 * 4);
  u16* tB     = (u16*)alloc((size_t)N * H_DIM * 2);
  u16* W2T    = (u16*)alloc((size_t)H_DIM * H_DIM * 2);
  float* dis  = (float*)alloc((size_t)N * 4);
  int* counts = (int*)alloc((size_t)N * 4);
  int* rank   = (int*)alloc((size_t)E * 4);
  int* csroff = (int*)alloc((size_t)(N + 1) * 4);
  int* csr    = (int*)alloc((size_t)E * 4);
  float* t3   = (float*)alloc((size_t)N * 2 * 4);
  int* bsum   = (int*)alloc((size_t)NB_SCAN * 4);
  int* boff   = (int*)alloc((size_t)NB_SCAN * 4);
  int8_t* xq  = (int8_t*)alloc((size_t)N * K1Q);
  float* sx   = (float*)alloc((size_t)N * 4);
  int8_t* w1q = (int8_t*)alloc((size_t)H_DIM * K1Q);
  float* sw   = (float*)alloc((size_t)H_DIM * 4);

  hipMemsetAsync(counts, 0, (size_t)N * 4, stream);
  k_histrank<<<(E + 255) / 256, 256, 0, stream>>>(dst, counts, rank, E);
  k_reduce<<<NB_SCAN, 256, 0, stream>>>(counts, bsum);
  k_scantop<<<1, 256, 0, stream>>>(bsum, boff, csroff + N);
  k_scanlocal<<<NB_SCAN, 256, 0, stream>>>(counts, boff, csroff, dis);
  k_place<<<(E + 255) / 256, 256, 0, stream>>>(src, dst, rank, csroff, csr, E);
  k_quantx<<<N / 4, 256, 0, stream>>>(x, xq, sx);
  k_prepw<<<H_DIM / 4 + H_DIM, 256, 0, stream>>>(W1, W2, w1q, sw, W2T);

  // layer 1 (int8 MFMA)
  k_mmA8<<<N / 64, 256, 0, stream>>>(xq, sx, w1q, sw, dis, tQ, rs4);
  k_agg<false><<<N / 4, 256, 0, stream>>>(tQ, rs4, csroff, csr, dis, b1, tB, nullptr, nullptr, N);
  // layer 2 (agg fused with layer-3 matmul -> t3)
  k_mmB<H_DIM><<<N / 64, 256, 0, stream>>>(tB, W2T, dis, tQ, rs4);
  k_agg<true><<<N / 4, 256, 0, stream>>>(tQ, rs4, csroff, csr, dis, b2, nullptr, W3, t3, N);
  // layer 3 aggregation fused with mean pool
  k_aggpool3<<<N_GRAPHS, 448, 0, stream>>>(t3, csroff, csr, dis, b3, out);
}